// Round 4
// baseline (82.771 us; speedup 1.0000x reference)
//
#include <hip/hip_runtime.h>
#include <cmath>

// Peaks3d: out[b,c,d,h,w] = relu( sum_k w[k] * (sum_c' x[b,c',d+k-3,h,w]) )
// Identical across output channel c. B=4, C=4, D=24, H=W=384. fp32 in/out.
//
// Memory-bound: 226.5 MB read + 226.5 MB write, exactly once each (minimum).
// R1: nt loads/stores (zero-reuse, bypass L2 alloc) +23%.
// R2: 64-thread blocks, 2304 blocks = exactly 9/CU, uniform -> +6%.
// R3 experiment: monotonic per-channel address order + two depth-phases so
// reads and writes interleave within a wave (DRAM turnaround smoothing);
// also keeps outstanding loads <= 60 < vmcnt cap 63.

#define DD 24
#define CC 4
#define HW4 36864   // 384*384/4 float4 columns per (b,c,d) plane

typedef float f4 __attribute__((ext_vector_type(4)));

struct W7 { float w[7]; };

__device__ __forceinline__ f4 conv_at(const f4* s, int d, const W7& wt) {
    f4 acc = (f4)0.0f;
#pragma unroll
    for (int k = 0; k < 7; ++k) {
        const int j = d + k - 3;            // compile-time after unroll
        if (j >= 0 && j < DD)
            acc += wt.w[k] * s[j];
    }
    f4 r;
    r.x = fmaxf(acc.x, 0.f);
    r.y = fmaxf(acc.y, 0.f);
    r.z = fmaxf(acc.z, 0.f);
    r.w = fmaxf(acc.w, 0.f);
    return r;
}

__global__ __launch_bounds__(64) void peaks3d_kernel(const f4* __restrict__ x,
                                                     f4* __restrict__ out,
                                                     W7 wt) {
    const int col = blockIdx.x * 64 + threadIdx.x;   // 0..36863
    const int b   = blockIdx.y;                      // 0..3
    const size_t base = (size_t)b * CC * DD * HW4 + col;
    const f4* xb = x + base;
    f4*       ob = out + base;

    f4 s[DD];

    // ---- Phase A: load depths [0,15), monotonic addresses per channel ----
#pragma unroll
    for (int d = 0; d < 15; ++d) s[d] = (f4)0.0f;
#pragma unroll
    for (int c = 0; c < CC; ++c)
#pragma unroll
        for (int d = 0; d < 15; ++d)
            s[d] += __builtin_nontemporal_load(xb + (size_t)(c * DD + d) * HW4);

    // compute outputs d=0..11 (need s[0..14]), store monotonic (c-outer)
    {
        f4 r[12];
#pragma unroll
        for (int d = 0; d < 12; ++d) r[d] = conv_at(s, d, wt);
#pragma unroll
        for (int c = 0; c < CC; ++c)
#pragma unroll
            for (int d = 0; d < 12; ++d)
                __builtin_nontemporal_store(r[d], ob + (size_t)(c * DD + d) * HW4);
    }

    // ---- Phase B: load depths [15,24) ----
#pragma unroll
    for (int d = 15; d < DD; ++d) s[d] = (f4)0.0f;
#pragma unroll
    for (int c = 0; c < CC; ++c)
#pragma unroll
        for (int d = 15; d < DD; ++d)
            s[d] += __builtin_nontemporal_load(xb + (size_t)(c * DD + d) * HW4);

    // compute outputs d=12..23 (need s[9..23]), store monotonic
    {
        f4 r[12];
#pragma unroll
        for (int d = 12; d < DD; ++d) r[d - 12] = conv_at(s, d, wt);
#pragma unroll
        for (int c = 0; c < CC; ++c)
#pragma unroll
            for (int d = 12; d < DD; ++d)
                __builtin_nontemporal_store(r[d - 12], ob + (size_t)(c * DD + d) * HW4);
    }
}

extern "C" void kernel_launch(void* const* d_in, const int* in_sizes, int n_in,
                              void* d_out, int out_size, void* d_ws, size_t ws_size,
                              hipStream_t stream) {
    const f4* x   = (const f4*)d_in[0];
    f4*       out = (f4*)d_out;

    // Faithful replication of the reference weight construction (double prec).
    W7 wt;
    {
        const double S = 1.5;
        double xs[7], w[7];
        double mean = 0.0;
        for (int i = 0; i < 7; ++i) {
            xs[i] = -9.0 + (double)i * (19.0 / 6.0);
            double g = exp(-(xs[i] * xs[i]) / (2.0 * S * S)) /
                       (sqrt(2.0 * M_PI) * S);
            w[i] = g * (xs[i] * xs[i] / (S * S * S * S) - 1.0) / (S * S);
            mean += w[i];
        }
        mean /= 7.0;
        double norm = 0.0;
        for (int i = 0; i < 7; ++i) {
            w[i] -= mean;
            norm += w[i] * xs[i] * xs[i];
        }
        norm *= 0.5;
        for (int i = 0; i < 7; ++i) wt.w[i] = (float)(-(w[i] / norm));
    }

    dim3 grid(HW4 / 64, 4);   // 576 x 4 = 2304 blocks of 64 threads = 9/CU
    peaks3d_kernel<<<grid, 64, 0, stream>>>(x, out, wt);
}

// Round 5
// 78.443 us; speedup vs baseline: 1.0552x; 1.0552x over previous
//
#include <hip/hip_runtime.h>
#include <cmath>

// Peaks3d: out[b,c,d,h,w] = relu( sum_k w[k] * (sum_c' x[b,c',d+k-3,h,w]) )
// Identical across output channel c. B=4, C=4, D=24, H=W=384. fp32 in/out.
//
// Memory-bound: 226.5 MB read + 226.5 MB write, exactly once each (minimum).
// R1: nt loads/stores (zero-reuse streams, bypass L2 alloc) +23%.
// R2: 64-thread blocks, 2304 blocks = exactly 9/CU, uniform work -> +6%.
//     5.80 TB/s effective = 92% of float4-copy ceiling (6.29 TB/s).
// R3: monotonic c-outer order + 2-phase split REGRESSED (-6%) -> reverted.
//     d-outer load order + per-d store interleave is the winning schedule.

#define DD 24
#define CC 4
#define HW4 36864   // 384*384/4 float4 columns per (b,c,d) plane

typedef float f4 __attribute__((ext_vector_type(4)));

struct W7 { float w[7]; };

__global__ __launch_bounds__(64, 3) void peaks3d_kernel(const f4* __restrict__ x,
                                                        f4* __restrict__ out,
                                                        W7 wt) {
    const int col = blockIdx.x * 64 + threadIdx.x;   // 0..36863
    const int b   = blockIdx.y;                      // 0..3
    const size_t base = (size_t)b * CC * DD * HW4 + col;
    const f4* xb = x + base;
    f4*       ob = out + base;

    // ---- channel sum: s[d] = sum_c x[b,c,d,col] ----
    f4 s[DD];
#pragma unroll
    for (int d = 0; d < DD; ++d) {
        f4 a0 = __builtin_nontemporal_load(xb + (size_t)(0 * DD + d) * HW4);
        f4 a1 = __builtin_nontemporal_load(xb + (size_t)(1 * DD + d) * HW4);
        f4 a2 = __builtin_nontemporal_load(xb + (size_t)(2 * DD + d) * HW4);
        f4 a3 = __builtin_nontemporal_load(xb + (size_t)(3 * DD + d) * HW4);
        s[d] = (a0 + a1) + (a2 + a3);
    }

    // ---- depth conv (cross-correlation, zero pad 3) + ReLU + broadcast ----
#pragma unroll
    for (int d = 0; d < DD; ++d) {
        f4 acc = (f4)0.0f;
#pragma unroll
        for (int k = 0; k < 7; ++k) {
            const int j = d + k - 3;           // compile-time after unroll
            if (j >= 0 && j < DD)
                acc += wt.w[k] * s[j];
        }
        f4 r;
        r.x = fmaxf(acc.x, 0.f);
        r.y = fmaxf(acc.y, 0.f);
        r.z = fmaxf(acc.z, 0.f);
        r.w = fmaxf(acc.w, 0.f);
#pragma unroll
        for (int c = 0; c < CC; ++c)
            __builtin_nontemporal_store(r, ob + (size_t)(c * DD + d) * HW4);
    }
}

extern "C" void kernel_launch(void* const* d_in, const int* in_sizes, int n_in,
                              void* d_out, int out_size, void* d_ws, size_t ws_size,
                              hipStream_t stream) {
    const f4* x   = (const f4*)d_in[0];
    f4*       out = (f4*)d_out;

    // Faithful replication of the reference weight construction (double prec).
    W7 wt;
    {
        const double S = 1.5;
        double xs[7], w[7];
        double mean = 0.0;
        for (int i = 0; i < 7; ++i) {
            xs[i] = -9.0 + (double)i * (19.0 / 6.0);
            double g = exp(-(xs[i] * xs[i]) / (2.0 * S * S)) /
                       (sqrt(2.0 * M_PI) * S);
            w[i] = g * (xs[i] * xs[i] / (S * S * S * S) - 1.0) / (S * S);
            mean += w[i];
        }
        mean /= 7.0;
        double norm = 0.0;
        for (int i = 0; i < 7; ++i) {
            w[i] -= mean;
            norm += w[i] * xs[i] * xs[i];
        }
        norm *= 0.5;
        for (int i = 0; i < 7; ++i) wt.w[i] = (float)(-(w[i] / norm));
    }

    dim3 grid(HW4 / 64, 4);   // 576 x 4 = 2304 blocks of 64 threads = 9/CU
    peaks3d_kernel<<<grid, 64, 0, stream>>>(x, out, wt);
}